// Round 4
// baseline (133.571 us; speedup 1.0000x reference)
//
#include <hip/hip_runtime.h>
#include <math.h>

#define BATCH 65536
#define ROWS_PER_BLOCK 64
#define DT_C 0.0166667f
#define NN_RATIO_C 0.3f

typedef __bf16 bf16x8 __attribute__((ext_vector_type(8)));
typedef unsigned short us8 __attribute__((ext_vector_type(8)));
typedef float f32x4 __attribute__((ext_vector_type(4)));

union FragU { us8 u; bf16x8 b; };

__device__ __forceinline__ unsigned short f2bf(float f) {
    union { __bf16 h; unsigned short u; } v;
    v.h = (__bf16)f;            // hardware RTNE cvt
    return v.u;
}
__device__ __forceinline__ float lrelu(float x) { return x > 0.0f ? x : 0.01f * x; }

// Block = 512 threads = 8 waves; wave w == muscle w.
//
// R5 change: 64 rows/block, 1024 blocks (was 128/512). Doubles TLP to
// 8 waves/SIMD (VGPR=48 <= 64 budget, pinned by __launch_bounds__(512,8))
// and halves the per-wave serial chain (2 loop iterations instead of 4).
// The kernel is latency-bound: zero-LDS main loop (R4, verified bit-identical
// absmax 3.9e-3) left dependent MFMA/pack chains as the critical path, and at
// the old geometry only 4 waves/SIMD were resident to hide them.
//
// R4 (kept): ZERO-LDS main loop. The MFMA contraction-position -> semantic-k
// map is an arbitrary bijection as long as A-frag and B-frag agree:
//   sigma(quad, j) = (j < 4) ? quad*4 + j : 16 + quad*4 + (j - 4)
// matches the k-indices a lane holds in its layer-n accumulators
// (acc0[r] -> k = quad*4+r, acc1[r] -> k = 16+quad*4+r). W2/W3 A-frags are
// loaded sigma-permuted (two contiguous f32x4 per row-tile), so layer-n
// outputs feed layer-(n+1) MFMAs directly in registers. No ds_write/ds_read.
//
// MFMA orientation (verified, absmax 3.9e-3): D[o][b] = sum_i W[o][i]*X[b][i]
//   A-frag = W[o=t*16+n16][pos], B-frag = X[b=n16][pos],
//   D lane = col b=n16, rows o=quad*4+reg.
__global__ __launch_bounds__(512, 8) void joint_kernel(
    const float* __restrict__ SS, const float* __restrict__ Alphas,
    const float* __restrict__ K0s, const float* __restrict__ K1s,
    const float* __restrict__ L0s, const float* __restrict__ L1s,
    const float* __restrict__ Ms, const float* __restrict__ Ivec,
    const float* __restrict__ Bv, const float* __restrict__ Kv,
    const float* __restrict__ W1, const float* __restrict__ b1,
    const float* __restrict__ W2, const float* __restrict__ b2,
    const float* __restrict__ W3, const float* __restrict__ b3,
    const float* __restrict__ W4, const float* __restrict__ b4,
    float* __restrict__ out)
{
    __shared__ float red_k[8][ROWS_PER_BLOCK];
    __shared__ float red_bf[8][ROWS_PER_BLOCK];

    const int tid  = threadIdx.x;
    const int lane = tid & 63;
    const int w    = tid >> 6;
    const int m    = __builtin_amdgcn_readfirstlane(w);
    const int n16  = lane & 15;
    const int quad = lane >> 4;

    const float ms = Ms[m];
    const float k0 = K0s[m], k1 = K1s[m], l0 = L0s[m], l1 = L1s[m];
    const float b4m = b4[m];

    // ---- weight fragments (loaded once per wave) ----
    FragU w1f[2], w2f[2], w3f[2];
    f32x4 bias1[2], bias2[2], bias3[2];
    #pragma unroll
    for (int t = 0; t < 2; ++t) {
        const int o = t * 16 + n16;
        // sigma-permuted K gather: positions j<4 take cols quad*4+j,
        // positions j>=4 take cols 16+quad*4+(j-4). Both contiguous f32x4.
        const float* p2 = W2 + m * 1024 + o * 32;
        const float* p3 = W3 + m * 1024 + o * 32;
        f32x4 a2 = *(const f32x4*)(p2 + quad * 4), c2 = *(const f32x4*)(p2 + 16 + quad * 4);
        f32x4 a3 = *(const f32x4*)(p3 + quad * 4), c3 = *(const f32x4*)(p3 + 16 + quad * 4);
        #pragma unroll
        for (int j = 0; j < 4; ++j) {
            w2f[t].u[j] = f2bf(a2[j]); w2f[t].u[4 + j] = f2bf(c2[j]);
            w3f[t].u[j] = f2bf(a3[j]); w3f[t].u[4 + j] = f2bf(c3[j]);
        }
        us8 z = {0,0,0,0,0,0,0,0};
        w1f[t].u = z;
        if (quad == 0) {
            // layer 1 keeps the natural map: only k=0,1,2 nonzero (quad 0)
            const float* p1 = W1 + m * 96 + o * 3;
            w1f[t].u[0] = f2bf(p1[0]);
            w1f[t].u[1] = f2bf(p1[1]);
            w1f[t].u[2] = f2bf(p1[2]);
        }
        bias1[t] = *(const f32x4*)(b1 + m * 32 + t * 16 + quad * 4);
        bias2[t] = *(const f32x4*)(b2 + m * 32 + t * 16 + quad * 4);
        bias3[t] = *(const f32x4*)(b3 + m * 32 + t * 16 + quad * 4);
    }
    const f32x4 w4a = *(const f32x4*)(W4 + m * 32 + quad * 4);
    const f32x4 w4b = *(const f32x4*)(W4 + m * 32 + 16 + quad * 4);

    #pragma unroll 1
    for (int s = 0; s < ROWS_PER_BLOCK / 16; s += 2) {
        float lv[2], dlv[2], av[2];
        FragU xf[2];
        #pragma unroll
        for (int p = 0; p < 2; ++p) {
            const int bb = blockIdx.x * ROWS_PER_BLOCK + (s + p) * 16 + n16;
            const float2 ssv = *(const float2*)&SS[2 * bb];
            float a = Alphas[8 * bb + m];
            a = fminf(fmaxf(a, 0.0f), 1.0f);
            av[p]  = a;
            lv[p]  = ssv.x * ms;
            dlv[p] = ssv.y * ms;
            us8 z = {0,0,0,0,0,0,0,0};
            xf[p].u = z;
            if (quad == 0) {
                xf[p].u[0] = f2bf(lv[p]);
                xf[p].u[1] = f2bf(dlv[p]);
                xf[p].u[2] = f2bf(a);
            }
        }

        f32x4 acc0[2], acc1[2];
        // ---- layer 1 ----
        #pragma unroll
        for (int p = 0; p < 2; ++p) {
            acc0[p] = __builtin_amdgcn_mfma_f32_16x16x32_bf16(w1f[0].b, xf[p].b, bias1[0], 0, 0, 0);
            acc1[p] = __builtin_amdgcn_mfma_f32_16x16x32_bf16(w1f[1].b, xf[p].b, bias1[1], 0, 0, 0);
        }
        // pack activations directly into sigma-layout B-frags (in registers)
        FragU hf[2];
        #pragma unroll
        for (int p = 0; p < 2; ++p) {
            #pragma unroll
            for (int r = 0; r < 4; ++r) {
                hf[p].u[r]     = f2bf(lrelu(acc0[p][r]));
                hf[p].u[4 + r] = f2bf(lrelu(acc1[p][r]));
            }
        }

        // ---- layer 2 ----
        #pragma unroll
        for (int p = 0; p < 2; ++p) {
            acc0[p] = __builtin_amdgcn_mfma_f32_16x16x32_bf16(w2f[0].b, hf[p].b, bias2[0], 0, 0, 0);
            acc1[p] = __builtin_amdgcn_mfma_f32_16x16x32_bf16(w2f[1].b, hf[p].b, bias2[1], 0, 0, 0);
        }
        #pragma unroll
        for (int p = 0; p < 2; ++p) {
            #pragma unroll
            for (int r = 0; r < 4; ++r) {
                hf[p].u[r]     = f2bf(lrelu(acc0[p][r]));
                hf[p].u[4 + r] = f2bf(lrelu(acc1[p][r]));
            }
        }

        // ---- layer 3 ----
        #pragma unroll
        for (int p = 0; p < 2; ++p) {
            acc0[p] = __builtin_amdgcn_mfma_f32_16x16x32_bf16(w3f[0].b, hf[p].b, bias3[0], 0, 0, 0);
            acc1[p] = __builtin_amdgcn_mfma_f32_16x16x32_bf16(w3f[1].b, hf[p].b, bias3[1], 0, 0, 0);
        }

        // ---- layer 4: 32->1 dot via regs + cross-quad shuffle reduce ----
        float dot[2];
        #pragma unroll
        for (int p = 0; p < 2; ++p) {
            float d = 0.0f;
            #pragma unroll
            for (int r = 0; r < 4; ++r) {
                d += lrelu(acc0[p][r]) * w4a[r];
                d += lrelu(acc1[p][r]) * w4b[r];
            }
            d += __shfl_xor(d, 16, 64);
            d += __shfl_xor(d, 32, 64);
            dot[p] = d;
        }

        if (quad == 0) {
            #pragma unroll
            for (int p = 0; p < 2; ++p) {
                const float x2 = 2.0f * (dot[p] + b4m);
                const float e2x = __expf(x2);
                const float nn = (1.0f - 2.0f / (e2x + 1.0f)) * NN_RATIO_C;
                const float kk = k0 + k1 * av[p];
                red_k[w][(s + p) * 16 + n16]  = kk * ms * ms;
                red_bf[w][(s + p) * 16 + n16] =
                    (kk * (l0 + l1 * av[p] - fabsf(lv[p])) + k1 * l1 * av[p] * av[p] * nn) * ms;
            }
        }
    }

    __syncthreads();

    if (tid < ROWS_PER_BLOCK) {
        float Ksum = 0.0f, BFsum = 0.0f;
        #pragma unroll
        for (int mm = 0; mm < 8; ++mm) {
            Ksum  += red_k[mm][tid];
            BFsum += red_bf[mm][tid];
        }

        const int b = blockIdx.x * ROWS_PER_BLOCK + tid;
        const float2 ssv = *(const float2*)&SS[2 * b];
        const float s0 = ssv.x, s1 = ssv.y;
        const float I  = Ivec[0];
        const float bv = Bv[0];
        const float kv = Kv[0];
        const float inv_I = 1.0f / I;

        const float A10 = -(Ksum + kv) * inv_I;
        const float D   = 2.0f * sqrtf(Ksum * I);
        const float A11 = -(D + bv) * inv_I;
        const float B10 = BFsum * inv_I;

        // Reduced 3x3 expm (verified): M=[[0,DT,0],[A10*DT,A11*DT,B10*DT],[0,0,0]]
        const float m01 = DT_C;
        const float m10 = A10 * DT_C, m11 = A11 * DT_C, m12 = B10 * DT_C;

        float p00 = 0.0f, p01 = m01, p02 = 0.0f;
        float p10 = m10,  p11 = m11, p12 = m12;
        float t00 = p00, t01 = p01, t02 = p02;
        float t10 = p10, t11 = p11, t12 = p12;
        #pragma unroll
        for (int k = 2; k <= 16; ++k) {
            float inv = 1.0f / (float)k;     // compile-time constant (unrolled)
            float q00 = (p01 * m10) * inv;
            float q01 = (p00 * m01 + p01 * m11) * inv;
            float q02 = (p01 * m12) * inv;
            float q10 = (p11 * m10) * inv;
            float q11 = (p10 * m01 + p11 * m11) * inv;
            float q12 = (p11 * m12) * inv;
            p00 = q00; p01 = q01; p02 = q02;
            p10 = q10; p11 = q11; p12 = q12;
            t00 += p00; t01 += p01; t02 += p02;
            t10 += p10; t11 += p11; t12 += p12;
        }
        const float E00 = 1.0f + t00, E01 = t01, c0 = t02;
        const float E10 = t10,        E11 = 1.0f + t11, c1 = t12;

        const float o0 = E00 * s0 + E01 * s1 + c0;
        const float o1 = E10 * s0 + E11 * s1 + c1;

        out[b] = o0;                               // output 0: SSout[:,0:1]
        float2 o01; o01.x = o0; o01.y = o1;        // output 1: SSout[:,:,0]
        *(float2*)&out[BATCH + 2 * b] = o01;       // coalesced 8B store
    }
}

extern "C" void kernel_launch(void* const* d_in, const int* in_sizes, int n_in,
                              void* d_out, int out_size, void* d_ws, size_t ws_size,
                              hipStream_t stream) {
    const float* SS     = (const float*)d_in[0];
    const float* Alphas = (const float*)d_in[1];
    const float* K0s    = (const float*)d_in[2];
    const float* K1s    = (const float*)d_in[3];
    const float* L0s    = (const float*)d_in[4];
    const float* L1s    = (const float*)d_in[5];
    const float* Ms     = (const float*)d_in[6];
    const float* I      = (const float*)d_in[7];
    const float* Bv     = (const float*)d_in[8];
    const float* Kv     = (const float*)d_in[9];
    const float* W1     = (const float*)d_in[10];
    const float* b1     = (const float*)d_in[11];
    const float* W2     = (const float*)d_in[12];
    const float* b2     = (const float*)d_in[13];
    const float* W3     = (const float*)d_in[14];
    const float* b3     = (const float*)d_in[15];
    const float* W4     = (const float*)d_in[16];
    const float* b4     = (const float*)d_in[17];
    float* out = (float*)d_out;

    joint_kernel<<<BATCH / ROWS_PER_BLOCK, 512, 0, stream>>>(
        SS, Alphas, K0s, K1s, L0s, L1s, Ms, I, Bv, Kv,
        W1, b1, W2, b2, W3, b3, W4, b4, out);
}

// Round 5
// 109.816 us; speedup vs baseline: 1.2163x; 1.2163x over previous
//
#include <hip/hip_runtime.h>
#include <math.h>

#define BATCH 65536
#define ROWS_PER_BLOCK 64
#define DT_C 0.0166667f
#define NN_RATIO_C 0.3f

typedef __bf16 bf16x8 __attribute__((ext_vector_type(8)));
typedef unsigned short us8 __attribute__((ext_vector_type(8)));
typedef float f32x4 __attribute__((ext_vector_type(4)));

union FragU { us8 u; bf16x8 b; };

__device__ __forceinline__ unsigned short f2bf(float f) {
    union { __bf16 h; unsigned short u; } v;
    v.h = (__bf16)f;            // hardware RTNE cvt
    return v.u;
}
__device__ __forceinline__ float lrelu(float x) { return x > 0.0f ? x : 0.01f * x; }

// Block = 512 threads = 8 waves; wave w == muscle w.
//
// R6 change: REVERT the min-waves clamp of R5. __launch_bounds__(512,8)
// forced VGPR 48->32 and spilled the long-lived weight/bias fragments to
// scratch: rocprof R4 showed WRITE_SIZE=68MB (output is 0.77MB!) and
// FETCH_SIZE=57MB -> kernel became scratch-bound at 49us/dispatch.
// At 48 VGPR the register file already allows 10 waves/SIMD, so occupancy
// is set by the GRID alone: keep 64 rows/block, 1024 blocks
// (4 blocks/CU x 8 waves = 32 waves/CU = HW max, 8 waves/SIMD).
//
// R4 (kept, verified bit-identical absmax 3.9e-3): ZERO-LDS main loop.
// The MFMA contraction-position -> semantic-k map is an arbitrary bijection
// as long as A-frag and B-frag agree:
//   sigma(quad, j) = (j < 4) ? quad*4 + j : 16 + quad*4 + (j - 4)
// matches the k-indices a lane holds in its layer-n accumulators
// (acc0[r] -> k = quad*4+r, acc1[r] -> k = 16+quad*4+r). W2/W3 A-frags are
// loaded sigma-permuted (two contiguous f32x4 per row-tile), so layer-n
// outputs feed layer-(n+1) MFMAs directly in registers. No ds_write/ds_read.
//
// MFMA orientation (verified, absmax 3.9e-3): D[o][b] = sum_i W[o][i]*X[b][i]
//   A-frag = W[o=t*16+n16][pos], B-frag = X[b=n16][pos],
//   D lane = col b=n16, rows o=quad*4+reg.
__global__ __launch_bounds__(512) void joint_kernel(
    const float* __restrict__ SS, const float* __restrict__ Alphas,
    const float* __restrict__ K0s, const float* __restrict__ K1s,
    const float* __restrict__ L0s, const float* __restrict__ L1s,
    const float* __restrict__ Ms, const float* __restrict__ Ivec,
    const float* __restrict__ Bv, const float* __restrict__ Kv,
    const float* __restrict__ W1, const float* __restrict__ b1,
    const float* __restrict__ W2, const float* __restrict__ b2,
    const float* __restrict__ W3, const float* __restrict__ b3,
    const float* __restrict__ W4, const float* __restrict__ b4,
    float* __restrict__ out)
{
    __shared__ float red_k[8][ROWS_PER_BLOCK];
    __shared__ float red_bf[8][ROWS_PER_BLOCK];

    const int tid  = threadIdx.x;
    const int lane = tid & 63;
    const int w    = tid >> 6;
    const int m    = __builtin_amdgcn_readfirstlane(w);
    const int n16  = lane & 15;
    const int quad = lane >> 4;

    const float ms = Ms[m];
    const float k0 = K0s[m], k1 = K1s[m], l0 = L0s[m], l1 = L1s[m];
    const float b4m = b4[m];

    // ---- weight fragments (loaded once per wave) ----
    FragU w1f[2], w2f[2], w3f[2];
    f32x4 bias1[2], bias2[2], bias3[2];
    #pragma unroll
    for (int t = 0; t < 2; ++t) {
        const int o = t * 16 + n16;
        // sigma-permuted K gather: positions j<4 take cols quad*4+j,
        // positions j>=4 take cols 16+quad*4+(j-4). Both contiguous f32x4.
        const float* p2 = W2 + m * 1024 + o * 32;
        const float* p3 = W3 + m * 1024 + o * 32;
        f32x4 a2 = *(const f32x4*)(p2 + quad * 4), c2 = *(const f32x4*)(p2 + 16 + quad * 4);
        f32x4 a3 = *(const f32x4*)(p3 + quad * 4), c3 = *(const f32x4*)(p3 + 16 + quad * 4);
        #pragma unroll
        for (int j = 0; j < 4; ++j) {
            w2f[t].u[j] = f2bf(a2[j]); w2f[t].u[4 + j] = f2bf(c2[j]);
            w3f[t].u[j] = f2bf(a3[j]); w3f[t].u[4 + j] = f2bf(c3[j]);
        }
        us8 z = {0,0,0,0,0,0,0,0};
        w1f[t].u = z;
        if (quad == 0) {
            // layer 1 keeps the natural map: only k=0,1,2 nonzero (quad 0)
            const float* p1 = W1 + m * 96 + o * 3;
            w1f[t].u[0] = f2bf(p1[0]);
            w1f[t].u[1] = f2bf(p1[1]);
            w1f[t].u[2] = f2bf(p1[2]);
        }
        bias1[t] = *(const f32x4*)(b1 + m * 32 + t * 16 + quad * 4);
        bias2[t] = *(const f32x4*)(b2 + m * 32 + t * 16 + quad * 4);
        bias3[t] = *(const f32x4*)(b3 + m * 32 + t * 16 + quad * 4);
    }
    const f32x4 w4a = *(const f32x4*)(W4 + m * 32 + quad * 4);
    const f32x4 w4b = *(const f32x4*)(W4 + m * 32 + 16 + quad * 4);

    #pragma unroll 1
    for (int s = 0; s < ROWS_PER_BLOCK / 16; s += 2) {
        float lv[2], dlv[2], av[2];
        FragU xf[2];
        #pragma unroll
        for (int p = 0; p < 2; ++p) {
            const int bb = blockIdx.x * ROWS_PER_BLOCK + (s + p) * 16 + n16;
            const float2 ssv = *(const float2*)&SS[2 * bb];
            float a = Alphas[8 * bb + m];
            a = fminf(fmaxf(a, 0.0f), 1.0f);
            av[p]  = a;
            lv[p]  = ssv.x * ms;
            dlv[p] = ssv.y * ms;
            us8 z = {0,0,0,0,0,0,0,0};
            xf[p].u = z;
            if (quad == 0) {
                xf[p].u[0] = f2bf(lv[p]);
                xf[p].u[1] = f2bf(dlv[p]);
                xf[p].u[2] = f2bf(a);
            }
        }

        f32x4 acc0[2], acc1[2];
        // ---- layer 1 ----
        #pragma unroll
        for (int p = 0; p < 2; ++p) {
            acc0[p] = __builtin_amdgcn_mfma_f32_16x16x32_bf16(w1f[0].b, xf[p].b, bias1[0], 0, 0, 0);
            acc1[p] = __builtin_amdgcn_mfma_f32_16x16x32_bf16(w1f[1].b, xf[p].b, bias1[1], 0, 0, 0);
        }
        // pack activations directly into sigma-layout B-frags (in registers)
        FragU hf[2];
        #pragma unroll
        for (int p = 0; p < 2; ++p) {
            #pragma unroll
            for (int r = 0; r < 4; ++r) {
                hf[p].u[r]     = f2bf(lrelu(acc0[p][r]));
                hf[p].u[4 + r] = f2bf(lrelu(acc1[p][r]));
            }
        }

        // ---- layer 2 ----
        #pragma unroll
        for (int p = 0; p < 2; ++p) {
            acc0[p] = __builtin_amdgcn_mfma_f32_16x16x32_bf16(w2f[0].b, hf[p].b, bias2[0], 0, 0, 0);
            acc1[p] = __builtin_amdgcn_mfma_f32_16x16x32_bf16(w2f[1].b, hf[p].b, bias2[1], 0, 0, 0);
        }
        #pragma unroll
        for (int p = 0; p < 2; ++p) {
            #pragma unroll
            for (int r = 0; r < 4; ++r) {
                hf[p].u[r]     = f2bf(lrelu(acc0[p][r]));
                hf[p].u[4 + r] = f2bf(lrelu(acc1[p][r]));
            }
        }

        // ---- layer 3 ----
        #pragma unroll
        for (int p = 0; p < 2; ++p) {
            acc0[p] = __builtin_amdgcn_mfma_f32_16x16x32_bf16(w3f[0].b, hf[p].b, bias3[0], 0, 0, 0);
            acc1[p] = __builtin_amdgcn_mfma_f32_16x16x32_bf16(w3f[1].b, hf[p].b, bias3[1], 0, 0, 0);
        }

        // ---- layer 4: 32->1 dot via regs + cross-quad shuffle reduce ----
        float dot[2];
        #pragma unroll
        for (int p = 0; p < 2; ++p) {
            float d = 0.0f;
            #pragma unroll
            for (int r = 0; r < 4; ++r) {
                d += lrelu(acc0[p][r]) * w4a[r];
                d += lrelu(acc1[p][r]) * w4b[r];
            }
            d += __shfl_xor(d, 16, 64);
            d += __shfl_xor(d, 32, 64);
            dot[p] = d;
        }

        if (quad == 0) {
            #pragma unroll
            for (int p = 0; p < 2; ++p) {
                const float x2 = 2.0f * (dot[p] + b4m);
                const float e2x = __expf(x2);
                const float nn = (1.0f - 2.0f / (e2x + 1.0f)) * NN_RATIO_C;
                const float kk = k0 + k1 * av[p];
                red_k[w][(s + p) * 16 + n16]  = kk * ms * ms;
                red_bf[w][(s + p) * 16 + n16] =
                    (kk * (l0 + l1 * av[p] - fabsf(lv[p])) + k1 * l1 * av[p] * av[p] * nn) * ms;
            }
        }
    }

    __syncthreads();

    if (tid < ROWS_PER_BLOCK) {
        float Ksum = 0.0f, BFsum = 0.0f;
        #pragma unroll
        for (int mm = 0; mm < 8; ++mm) {
            Ksum  += red_k[mm][tid];
            BFsum += red_bf[mm][tid];
        }

        const int b = blockIdx.x * ROWS_PER_BLOCK + tid;
        const float2 ssv = *(const float2*)&SS[2 * b];
        const float s0 = ssv.x, s1 = ssv.y;
        const float I  = Ivec[0];
        const float bv = Bv[0];
        const float kv = Kv[0];
        const float inv_I = 1.0f / I;

        const float A10 = -(Ksum + kv) * inv_I;
        const float D   = 2.0f * sqrtf(Ksum * I);
        const float A11 = -(D + bv) * inv_I;
        const float B10 = BFsum * inv_I;

        // Reduced 3x3 expm (verified): M=[[0,DT,0],[A10*DT,A11*DT,B10*DT],[0,0,0]]
        const float m01 = DT_C;
        const float m10 = A10 * DT_C, m11 = A11 * DT_C, m12 = B10 * DT_C;

        float p00 = 0.0f, p01 = m01, p02 = 0.0f;
        float p10 = m10,  p11 = m11, p12 = m12;
        float t00 = p00, t01 = p01, t02 = p02;
        float t10 = p10, t11 = p11, t12 = p12;
        #pragma unroll
        for (int k = 2; k <= 16; ++k) {
            float inv = 1.0f / (float)k;     // compile-time constant (unrolled)
            float q00 = (p01 * m10) * inv;
            float q01 = (p00 * m01 + p01 * m11) * inv;
            float q02 = (p01 * m12) * inv;
            float q10 = (p11 * m10) * inv;
            float q11 = (p10 * m01 + p11 * m11) * inv;
            float q12 = (p11 * m12) * inv;
            p00 = q00; p01 = q01; p02 = q02;
            p10 = q10; p11 = q11; p12 = q12;
            t00 += p00; t01 += p01; t02 += p02;
            t10 += p10; t11 += p11; t12 += p12;
        }
        const float E00 = 1.0f + t00, E01 = t01, c0 = t02;
        const float E10 = t10,        E11 = 1.0f + t11, c1 = t12;

        const float o0 = E00 * s0 + E01 * s1 + c0;
        const float o1 = E10 * s0 + E11 * s1 + c1;

        out[b] = o0;                               // output 0: SSout[:,0:1]
        float2 o01; o01.x = o0; o01.y = o1;        // output 1: SSout[:,:,0]
        *(float2*)&out[BATCH + 2 * b] = o01;       // coalesced 8B store
    }
}

extern "C" void kernel_launch(void* const* d_in, const int* in_sizes, int n_in,
                              void* d_out, int out_size, void* d_ws, size_t ws_size,
                              hipStream_t stream) {
    const float* SS     = (const float*)d_in[0];
    const float* Alphas = (const float*)d_in[1];
    const float* K0s    = (const float*)d_in[2];
    const float* K1s    = (const float*)d_in[3];
    const float* L0s    = (const float*)d_in[4];
    const float* L1s    = (const float*)d_in[5];
    const float* Ms     = (const float*)d_in[6];
    const float* I      = (const float*)d_in[7];
    const float* Bv     = (const float*)d_in[8];
    const float* Kv     = (const float*)d_in[9];
    const float* W1     = (const float*)d_in[10];
    const float* b1     = (const float*)d_in[11];
    const float* W2     = (const float*)d_in[12];
    const float* b2     = (const float*)d_in[13];
    const float* W3     = (const float*)d_in[14];
    const float* b3     = (const float*)d_in[15];
    const float* W4     = (const float*)d_in[16];
    const float* b4     = (const float*)d_in[17];
    float* out = (float*)d_out;

    joint_kernel<<<BATCH / ROWS_PER_BLOCK, 512, 0, stream>>>(
        SS, Alphas, K0s, K1s, L0s, L1s, Ms, I, Bv, Kv,
        W1, b1, W2, b2, W3, b3, W4, b4, out);
}

// Round 6
// 103.629 us; speedup vs baseline: 1.2889x; 1.0597x over previous
//
#include <hip/hip_runtime.h>
#include <math.h>

#define BATCH 65536
#define ROWS_PER_BLOCK 128
#define DT_C 0.0166667f
#define NN_RATIO_C 0.3f

typedef __bf16 bf16x8 __attribute__((ext_vector_type(8)));
typedef unsigned short us8 __attribute__((ext_vector_type(8)));
typedef float f32x4 __attribute__((ext_vector_type(4)));

union FragU { us8 u; bf16x8 b; };

__device__ __forceinline__ unsigned short f2bf(float f) {
    union { __bf16 h; unsigned short u; } v;
    v.h = (__bf16)f;            // hardware RTNE cvt
    return v.u;
}
__device__ __forceinline__ float lrelu(float x) { return x > 0.0f ? x : 0.01f * x; }

// Block = 512 threads = 8 waves; wave w == muscle w; 128 rows/block, 512 blocks.
//
// R7 change: depth-1 software pipeline on the per-iteration input loads.
// Geometry evidence: 128-row/512-block = 104.1us beats 64-row/1024-block =
// 109.8us (R6) -> occupancy was NOT the bottleneck; revert to 128-row.
// With '#pragma unroll 1' the compiler cannot hoist iteration s+2's
// SS/Alphas loads across the back-edge (exec-masked LDS writes block it),
// so each iteration eats ~900cy of cold-HBM latency serially. Explicit
// ss_nxt/al_nxt registers issue the next iteration's loads BEFORE the
// current iteration's MFMA/pack chain -> latency hides under ~1 full
// iteration of compute. All arrays p-indexed inside unrolled loops only
// (no runtime indexing -> no scratch). VGPR 48 -> ~60, still < 64 step.
//
// R5 lesson (kept reverted): NO min-waves __launch_bounds__ clamp - (512,8)
// forced VGPR 32 and spilled weight fragments (68MB scratch writes, 49.5us).
//
// R4 (kept, verified bit-identical absmax 3.9e-3): ZERO-LDS main loop.
// sigma(quad, j) = (j < 4) ? quad*4 + j : 16 + quad*4 + (j - 4) matches the
// k-indices a lane holds in its layer-n accumulators, so sigma-permuted
// W2/W3 A-frags let layer-n outputs feed layer-(n+1) MFMAs directly in
// registers. No ds_write/ds_read transpose.
//
// MFMA orientation (verified): D[o][b] = sum_i W[o][i]*X[b][i]
//   A-frag = W[o=t*16+n16][pos], B-frag = X[b=n16][pos],
//   D lane = col b=n16, rows o=quad*4+reg.
__global__ __launch_bounds__(512) void joint_kernel(
    const float* __restrict__ SS, const float* __restrict__ Alphas,
    const float* __restrict__ K0s, const float* __restrict__ K1s,
    const float* __restrict__ L0s, const float* __restrict__ L1s,
    const float* __restrict__ Ms, const float* __restrict__ Ivec,
    const float* __restrict__ Bv, const float* __restrict__ Kv,
    const float* __restrict__ W1, const float* __restrict__ b1,
    const float* __restrict__ W2, const float* __restrict__ b2,
    const float* __restrict__ W3, const float* __restrict__ b3,
    const float* __restrict__ W4, const float* __restrict__ b4,
    float* __restrict__ out)
{
    __shared__ float red_k[8][ROWS_PER_BLOCK];
    __shared__ float red_bf[8][ROWS_PER_BLOCK];

    const int tid  = threadIdx.x;
    const int lane = tid & 63;
    const int w    = tid >> 6;
    const int m    = __builtin_amdgcn_readfirstlane(w);
    const int n16  = lane & 15;
    const int quad = lane >> 4;

    const float ms = Ms[m];
    const float k0 = K0s[m], k1 = K1s[m], l0 = L0s[m], l1 = L1s[m];
    const float b4m = b4[m];

    // ---- weight fragments (loaded once per wave) ----
    FragU w1f[2], w2f[2], w3f[2];
    f32x4 bias1[2], bias2[2], bias3[2];
    #pragma unroll
    for (int t = 0; t < 2; ++t) {
        const int o = t * 16 + n16;
        // sigma-permuted K gather: positions j<4 take cols quad*4+j,
        // positions j>=4 take cols 16+quad*4+(j-4). Both contiguous f32x4.
        const float* p2 = W2 + m * 1024 + o * 32;
        const float* p3 = W3 + m * 1024 + o * 32;
        f32x4 a2 = *(const f32x4*)(p2 + quad * 4), c2 = *(const f32x4*)(p2 + 16 + quad * 4);
        f32x4 a3 = *(const f32x4*)(p3 + quad * 4), c3 = *(const f32x4*)(p3 + 16 + quad * 4);
        #pragma unroll
        for (int j = 0; j < 4; ++j) {
            w2f[t].u[j] = f2bf(a2[j]); w2f[t].u[4 + j] = f2bf(c2[j]);
            w3f[t].u[j] = f2bf(a3[j]); w3f[t].u[4 + j] = f2bf(c3[j]);
        }
        us8 z = {0,0,0,0,0,0,0,0};
        w1f[t].u = z;
        if (quad == 0) {
            // layer 1 keeps the natural map: only k=0,1,2 nonzero (quad 0)
            const float* p1 = W1 + m * 96 + o * 3;
            w1f[t].u[0] = f2bf(p1[0]);
            w1f[t].u[1] = f2bf(p1[1]);
            w1f[t].u[2] = f2bf(p1[2]);
        }
        bias1[t] = *(const f32x4*)(b1 + m * 32 + t * 16 + quad * 4);
        bias2[t] = *(const f32x4*)(b2 + m * 32 + t * 16 + quad * 4);
        bias3[t] = *(const f32x4*)(b3 + m * 32 + t * 16 + quad * 4);
    }
    const f32x4 w4a = *(const f32x4*)(W4 + m * 32 + quad * 4);
    const f32x4 w4b = *(const f32x4*)(W4 + m * 32 + 16 + quad * 4);

    const int row0 = blockIdx.x * ROWS_PER_BLOCK + n16;

    // ---- depth-1 input pipeline: cur = slots s,s+1; nxt = slots s+2,s+3 ----
    float2 ss_cur[2], ss_nxt[2];
    float  al_cur[2], al_nxt[2];
    #pragma unroll
    for (int p = 0; p < 2; ++p) {
        const int bb = row0 + p * 16;
        ss_cur[p] = *(const float2*)&SS[2 * bb];
        al_cur[p] = Alphas[8 * bb + m];
    }

    #pragma unroll 1
    for (int s = 0; s < ROWS_PER_BLOCK / 16; s += 2) {
        // issue next iteration's loads FIRST (index clamped mod 8: last
        // iteration redundantly re-loads slot 0/1 - branchless, harmless)
        const int sn = (s + 2) & (ROWS_PER_BLOCK / 16 - 1);
        #pragma unroll
        for (int p = 0; p < 2; ++p) {
            const int bb = row0 + (sn + p) * 16;
            ss_nxt[p] = *(const float2*)&SS[2 * bb];
            al_nxt[p] = Alphas[8 * bb + m];
        }

        float lv[2], dlv[2], av[2];
        FragU xf[2];
        #pragma unroll
        for (int p = 0; p < 2; ++p) {
            float a = fminf(fmaxf(al_cur[p], 0.0f), 1.0f);
            av[p]  = a;
            lv[p]  = ss_cur[p].x * ms;
            dlv[p] = ss_cur[p].y * ms;
            us8 z = {0,0,0,0,0,0,0,0};
            xf[p].u = z;
            if (quad == 0) {
                xf[p].u[0] = f2bf(lv[p]);
                xf[p].u[1] = f2bf(dlv[p]);
                xf[p].u[2] = f2bf(a);
            }
        }

        f32x4 acc0[2], acc1[2];
        // ---- layer 1 ----
        #pragma unroll
        for (int p = 0; p < 2; ++p) {
            acc0[p] = __builtin_amdgcn_mfma_f32_16x16x32_bf16(w1f[0].b, xf[p].b, bias1[0], 0, 0, 0);
            acc1[p] = __builtin_amdgcn_mfma_f32_16x16x32_bf16(w1f[1].b, xf[p].b, bias1[1], 0, 0, 0);
        }
        // pack activations directly into sigma-layout B-frags (in registers)
        FragU hf[2];
        #pragma unroll
        for (int p = 0; p < 2; ++p) {
            #pragma unroll
            for (int r = 0; r < 4; ++r) {
                hf[p].u[r]     = f2bf(lrelu(acc0[p][r]));
                hf[p].u[4 + r] = f2bf(lrelu(acc1[p][r]));
            }
        }

        // ---- layer 2 ----
        #pragma unroll
        for (int p = 0; p < 2; ++p) {
            acc0[p] = __builtin_amdgcn_mfma_f32_16x16x32_bf16(w2f[0].b, hf[p].b, bias2[0], 0, 0, 0);
            acc1[p] = __builtin_amdgcn_mfma_f32_16x16x32_bf16(w2f[1].b, hf[p].b, bias2[1], 0, 0, 0);
        }
        #pragma unroll
        for (int p = 0; p < 2; ++p) {
            #pragma unroll
            for (int r = 0; r < 4; ++r) {
                hf[p].u[r]     = f2bf(lrelu(acc0[p][r]));
                hf[p].u[4 + r] = f2bf(lrelu(acc1[p][r]));
            }
        }

        // ---- layer 3 ----
        #pragma unroll
        for (int p = 0; p < 2; ++p) {
            acc0[p] = __builtin_amdgcn_mfma_f32_16x16x32_bf16(w3f[0].b, hf[p].b, bias3[0], 0, 0, 0);
            acc1[p] = __builtin_amdgcn_mfma_f32_16x16x32_bf16(w3f[1].b, hf[p].b, bias3[1], 0, 0, 0);
        }

        // ---- layer 4: 32->1 dot via regs + cross-quad shuffle reduce ----
        float dot[2];
        #pragma unroll
        for (int p = 0; p < 2; ++p) {
            float d = 0.0f;
            #pragma unroll
            for (int r = 0; r < 4; ++r) {
                d += lrelu(acc0[p][r]) * w4a[r];
                d += lrelu(acc1[p][r]) * w4b[r];
            }
            d += __shfl_xor(d, 16, 64);
            d += __shfl_xor(d, 32, 64);
            dot[p] = d;
        }

        if (quad == 0) {
            #pragma unroll
            for (int p = 0; p < 2; ++p) {
                const float x2 = 2.0f * (dot[p] + b4m);
                const float e2x = __expf(x2);
                const float nn = (1.0f - 2.0f / (e2x + 1.0f)) * NN_RATIO_C;
                const float kk = k0 + k1 * av[p];
                red_k[w][(s + p) * 16 + n16]  = kk * ms * ms;
                red_bf[w][(s + p) * 16 + n16] =
                    (kk * (l0 + l1 * av[p] - fabsf(lv[p])) + k1 * l1 * av[p] * av[p] * nn) * ms;
            }
        }

        // rotate pipeline registers
        #pragma unroll
        for (int p = 0; p < 2; ++p) {
            ss_cur[p] = ss_nxt[p];
            al_cur[p] = al_nxt[p];
        }
    }

    __syncthreads();

    if (tid < ROWS_PER_BLOCK) {
        float Ksum = 0.0f, BFsum = 0.0f;
        #pragma unroll
        for (int mm = 0; mm < 8; ++mm) {
            Ksum  += red_k[mm][tid];
            BFsum += red_bf[mm][tid];
        }

        const int b = blockIdx.x * ROWS_PER_BLOCK + tid;
        const float2 ssv = *(const float2*)&SS[2 * b];
        const float s0 = ssv.x, s1 = ssv.y;
        const float I  = Ivec[0];
        const float bv = Bv[0];
        const float kv = Kv[0];
        const float inv_I = 1.0f / I;

        const float A10 = -(Ksum + kv) * inv_I;
        const float D   = 2.0f * sqrtf(Ksum * I);
        const float A11 = -(D + bv) * inv_I;
        const float B10 = BFsum * inv_I;

        // Reduced 3x3 expm (verified): M=[[0,DT,0],[A10*DT,A11*DT,B10*DT],[0,0,0]]
        const float m01 = DT_C;
        const float m10 = A10 * DT_C, m11 = A11 * DT_C, m12 = B10 * DT_C;

        float p00 = 0.0f, p01 = m01, p02 = 0.0f;
        float p10 = m10,  p11 = m11, p12 = m12;
        float t00 = p00, t01 = p01, t02 = p02;
        float t10 = p10, t11 = p11, t12 = p12;
        #pragma unroll
        for (int k = 2; k <= 16; ++k) {
            float inv = 1.0f / (float)k;     // compile-time constant (unrolled)
            float q00 = (p01 * m10) * inv;
            float q01 = (p00 * m01 + p01 * m11) * inv;
            float q02 = (p01 * m12) * inv;
            float q10 = (p11 * m10) * inv;
            float q11 = (p10 * m01 + p11 * m11) * inv;
            float q12 = (p11 * m12) * inv;
            p00 = q00; p01 = q01; p02 = q02;
            p10 = q10; p11 = q11; p12 = q12;
            t00 += p00; t01 += p01; t02 += p02;
            t10 += p10; t11 += p11; t12 += p12;
        }
        const float E00 = 1.0f + t00, E01 = t01, c0 = t02;
        const float E10 = t10,        E11 = 1.0f + t11, c1 = t12;

        const float o0 = E00 * s0 + E01 * s1 + c0;
        const float o1 = E10 * s0 + E11 * s1 + c1;

        out[b] = o0;                               // output 0: SSout[:,0:1]
        float2 o01; o01.x = o0; o01.y = o1;        // output 1: SSout[:,:,0]
        *(float2*)&out[BATCH + 2 * b] = o01;       // coalesced 8B store
    }
}

extern "C" void kernel_launch(void* const* d_in, const int* in_sizes, int n_in,
                              void* d_out, int out_size, void* d_ws, size_t ws_size,
                              hipStream_t stream) {
    const float* SS     = (const float*)d_in[0];
    const float* Alphas = (const float*)d_in[1];
    const float* K0s    = (const float*)d_in[2];
    const float* K1s    = (const float*)d_in[3];
    const float* L0s    = (const float*)d_in[4];
    const float* L1s    = (const float*)d_in[5];
    const float* Ms     = (const float*)d_in[6];
    const float* I      = (const float*)d_in[7];
    const float* Bv     = (const float*)d_in[8];
    const float* Kv     = (const float*)d_in[9];
    const float* W1     = (const float*)d_in[10];
    const float* b1     = (const float*)d_in[11];
    const float* W2     = (const float*)d_in[12];
    const float* b2     = (const float*)d_in[13];
    const float* W3     = (const float*)d_in[14];
    const float* b3     = (const float*)d_in[15];
    const float* W4     = (const float*)d_in[16];
    const float* b4     = (const float*)d_in[17];
    float* out = (float*)d_out;

    joint_kernel<<<BATCH / ROWS_PER_BLOCK, 512, 0, stream>>>(
        SS, Alphas, K0s, K1s, L0s, L1s, Ms, I, Bv, Kv,
        W1, b1, W2, b2, W3, b3, W4, b4, out);
}